// Round 15
// baseline (10616.838 us; speedup 1.0000x reference)
//
#include <hip/hip_runtime.h>
#include <math.h>

// leaky_current_RNN: B=128, T=512, I=4, H=512, O=3, alpha=0.5, n_reg=256.
// R15 = R14 with the staging bug fixed: win_s was guarded by tid < II*HH
// (=2048) with only 1024 threads -> win_s[2..3] uninitialized. Now staged
// with a grid-stride loop. Structure unchanged: single-block-per-row,
// 1024-thread blocks (16 waves, waves_per_eu(4,4) -> 512-reg budget) hold
// ALL of W_rec in registers (256 f32/thread); 128 blocks, one batch row
// each, recurrence synced by LDS barriers only (no LLC exchange, no
// cooperative launch). Wave w owns k-window [32w,32w+32); per step:
// 32 readlane + 128 pk_fma, 16-way split-k via sc[512][17], 512 finalize.

#define BB 128
#define TT 512
#define II 4
#define HH 512
#define OO 3
#define NREG_ 256

#define NTHREADS 1024

typedef unsigned long long u64;
typedef unsigned int u32;
typedef __attribute__((ext_vector_type(2))) float f32x2;

__device__ __forceinline__ float fast_tanh(float x) {
    float ax = fabsf(x);
    float e  = __expf(2.0f * ax);
    float r  = 1.0f - 2.0f * __builtin_amdgcn_rcpf(e + 1.0f);
    return copysignf(r, x);
}
// LDS-only barrier (global hidden-stores stay in flight).
__device__ __forceinline__ void bar_lds() {
    asm volatile("s_waitcnt lgkmcnt(0)" ::: "memory");
    __builtin_amdgcn_sched_barrier(0);
    __builtin_amdgcn_s_barrier();
    __builtin_amdgcn_sched_barrier(0);
}

#define R32(M) M(0) M(1) M(2) M(3) M(4) M(5) M(6) M(7) \
               M(8) M(9) M(10) M(11) M(12) M(13) M(14) M(15) \
               M(16) M(17) M(18) M(19) M(20) M(21) M(22) M(23) \
               M(24) M(25) M(26) M(27) M(28) M(29) M(30) M(31)

// Weight pairs for k = 32*wid + KK: w_j = (W[k][lane+128j], W[k][lane+64+128j])
#define WLDK(KK) \
    f32x2 w##KK##_0, w##KK##_1, w##KK##_2, w##KK##_3; \
    w##KK##_0.x = Wp[(size_t)(KK)*HH];       w##KK##_0.y = Wp[(size_t)(KK)*HH + 64]; \
    w##KK##_1.x = Wp[(size_t)(KK)*HH + 128]; w##KK##_1.y = Wp[(size_t)(KK)*HH + 192]; \
    w##KK##_2.x = Wp[(size_t)(KK)*HH + 256]; w##KK##_2.y = Wp[(size_t)(KK)*HH + 320]; \
    w##KK##_3.x = Wp[(size_t)(KK)*HH + 384]; w##KK##_3.y = Wp[(size_t)(KK)*HH + 448];

// 4 pk_fma per k: scalar a[k] broadcast to both halves (op_sel_hi[0]=0).
#define MVK(KK) { \
    u32 s_ = __builtin_amdgcn_readlane(__float_as_uint(ar), (KK)); \
    u64 ss = (u64)s_; \
    asm("v_pk_fma_f32 %0, %4, %5, %0 op_sel_hi:[0,1,1]\n\t" \
        "v_pk_fma_f32 %1, %4, %6, %1 op_sel_hi:[0,1,1]\n\t" \
        "v_pk_fma_f32 %2, %4, %7, %2 op_sel_hi:[0,1,1]\n\t" \
        "v_pk_fma_f32 %3, %4, %8, %3 op_sel_hi:[0,1,1]" \
        : "+v"(acc0), "+v"(acc1), "+v"(acc2), "+v"(acc3) \
        : "s"(ss), "v"(w##KK##_0), "v"(w##KK##_1), "v"(w##KK##_2), "v"(w##KK##_3)); }

__global__ __launch_bounds__(NTHREADS) __attribute__((amdgpu_waves_per_eu(4, 4)))
void rnn_main(const float* __restrict__ x,
              const float* __restrict__ h0,
              const float* __restrict__ W_rec,
              const float* __restrict__ W_in,
              const float* __restrict__ bias_rec,
              const float* __restrict__ bias_in,
              float* __restrict__ hidden,      // (T+1, B, H) region of d_out
              float* __restrict__ partials)    // [BB] per-row reg partial
{
    const int tid  = threadIdx.x;
    const int r    = blockIdx.x;              // batch row, 0..127
    const int wid  = tid >> 6;                // 0..15: k-window [32w, 32w+32)
    const int lane = tid & 63;

    __shared__ float a_lds[2][HH];            // tanh(h_t), double-buffered
    __shared__ float sc[HH][17];              // split-k partials (pad 17)
    __shared__ float xbuf[TT * II];           // this row's x
    __shared__ float win_s[II][HH];
    __shared__ float ub_s[HH];
    __shared__ float red_s[NTHREADS / 64];

    // ---- one-time staging (ALL loops grid-stride: sizes exceed blockDim) --
    for (int idx = tid; idx < TT * II; idx += NTHREADS)
        xbuf[idx] = x[(size_t)r * (TT * II) + idx];
    for (int idx = tid; idx < II * HH; idx += NTHREADS) {   // R14 bug fixed
        int i = idx >> 9, j = idx & (HH - 1);
        win_s[i][j] = W_in[i * HH + j];
    }
    if (tid < HH)
        ub_s[tid] = bias_rec[tid] + bias_in[tid];

    // ---- full W_rec into registers: 256 floats/thread ----
    const float* Wp = W_rec + (size_t)(wid * 32) * HH + lane;
    R32(WLDK)

    // ---- prologue: a_0 = tanh(h0), hidden[0] = h0 ----
    float hprev = 0.0f, zprev = 0.0f, racc = 0.0f;
    if (tid < HH) {
        hprev = h0[(size_t)r * HH + tid];
        a_lds[0][tid] = fast_tanh(hprev);
        hidden[(size_t)r * HH + tid] = hprev;
    }
    __syncthreads();

#pragma unroll 1
    for (int t = 0; t < TT; ++t) {
        const int cur = t & 1;
        const int nxt = cur ^ 1;

        // ---- matvec: all 16 waves, k-window owned by wave ----
        {
            float ar = a_lds[cur][wid * 32 + (lane & 31)];  // 2-way broadcast
            f32x2 acc0 = {0.0f, 0.0f};
            f32x2 acc1 = {0.0f, 0.0f};
            f32x2 acc2 = {0.0f, 0.0f};
            f32x2 acc3 = {0.0f, 0.0f};
            R32(MVK)
            sc[lane      ][wid] = acc0.x;  sc[lane + 64 ][wid] = acc0.y;
            sc[lane + 128][wid] = acc1.x;  sc[lane + 192][wid] = acc1.y;
            sc[lane + 256][wid] = acc2.x;  sc[lane + 320][wid] = acc2.y;
            sc[lane + 384][wid] = acc3.x;  sc[lane + 448][wid] = acc3.y;
        }
        bar_lds();

        // ---- finalize: 512 threads, one column each ----
        if (tid < HH) {
            const int j = tid;
            float s0 = sc[j][0],  s1 = sc[j][1],  s2 = sc[j][2],  s3 = sc[j][3];
            float s4 = sc[j][4],  s5 = sc[j][5],  s6 = sc[j][6],  s7 = sc[j][7];
            float s8 = sc[j][8],  s9 = sc[j][9],  sa = sc[j][10], sb = sc[j][11];
            float sd = sc[j][12], se = sc[j][13], sf = sc[j][14], sg = sc[j][15];
            float z = (((s0 + s1) + (s2 + s3)) + ((s4 + s5) + (s6 + s7)))
                    + (((s8 + s9) + (sa + sb)) + ((sd + se) + (sf + sg)));
            z += ub_s[j];
            const float* xr = &xbuf[t * II];
            z = fmaf(xr[0], win_s[0][j], z);
            z = fmaf(xr[1], win_s[1][j], z);
            z = fmaf(xr[2], win_s[2][j], z);
            z = fmaf(xr[3], win_s[3][j], z);
            float hn = 0.5f * hprev + 0.5f * z;
            a_lds[nxt][j] = fast_tanh(hn);
            hidden[(size_t)(t + 1) * BB * HH + (size_t)r * HH + j] = hn;
            if (j < NREG_) {
                float d1 = hn - hprev;
                racc = fmaf(d1, d1, racc);
                if (t > 0) { float d2 = z - zprev; racc = fmaf(d2, d2, racc); }
                zprev = z;
            }
            hprev = hn;
        }
        bar_lds();
    }

    // ---- block-reduce reg partial ----
    for (int off = 32; off; off >>= 1) racc += __shfl_down(racc, off);
    if ((tid & 63) == 0) red_s[tid >> 6] = racc;
    __syncthreads();
    if (tid == 0) {
        float s = 0.0f;
        for (int i = 0; i < NTHREADS / 64; ++i) s += red_s[i];
        partials[r] = s;
    }
}

// outputs[b][t][:] = hidden[t+1][b][:] @ W_out   (one wave per (b,t))
__global__ __launch_bounds__(256)
void rnn_out(const float* __restrict__ hidden,
             const float* __restrict__ W_out,
             float* __restrict__ outputs)
{
    __shared__ float wout_s[HH * OO];
    const int tid = threadIdx.x;
    for (int i = tid; i < HH * OO; i += 256) wout_s[i] = W_out[i];
    __syncthreads();

    const int gid  = blockIdx.x * 4 + (tid >> 6);
    const int lane = tid & 63;
    const int b = gid >> 9;
    const int t = gid & (TT - 1);
    const float* hp = hidden + (size_t)(t + 1) * BB * HH + (size_t)b * HH;

    float o0 = 0.0f, o1 = 0.0f, o2 = 0.0f;
#pragma unroll
    for (int q = 0; q < 8; ++q) {
        int k = lane + 64 * q;
        float hv = hp[k];
        o0 = fmaf(hv, wout_s[k * 3 + 0], o0);
        o1 = fmaf(hv, wout_s[k * 3 + 1], o1);
        o2 = fmaf(hv, wout_s[k * 3 + 2], o2);
    }
    for (int off = 32; off; off >>= 1) {
        o0 += __shfl_down(o0, off);
        o1 += __shfl_down(o1, off);
        o2 += __shfl_down(o2, off);
    }
    if (lane == 0) {
        float* op = outputs + (size_t)(b * TT + t) * OO;
        op[0] = o0; op[1] = o1; op[2] = o2;
    }
}

__global__ __launch_bounds__(128)
void rnn_tcr(const float* __restrict__ partials, float* __restrict__ tcr)
{
    __shared__ float red[2];
    const int tid = threadIdx.x;
    float v = partials[tid];                  // BB == 128 == blockDim
    for (int off = 32; off; off >>= 1) v += __shfl_down(v, off);
    if ((tid & 63) == 0) red[tid >> 6] = v;
    __syncthreads();
    if (tid == 0)
        *tcr = (red[0] + red[1]) * (1.0f / ((float)TT * (float)BB * (float)NREG_));
}

extern "C" void kernel_launch(void* const* d_in, const int* in_sizes, int n_in,
                              void* d_out, int out_size, void* d_ws, size_t ws_size,
                              hipStream_t stream)
{
    (void)in_sizes; (void)n_in; (void)out_size; (void)ws_size;

    const float* x     = (const float*)d_in[0];
    const float* h0    = (const float*)d_in[1];
    const float* W_rec = (const float*)d_in[2];
    const float* W_in  = (const float*)d_in[3];
    const float* W_out = (const float*)d_in[4];
    const float* brec  = (const float*)d_in[5];
    const float* bin   = (const float*)d_in[6];

    float* out     = (float*)d_out;
    float* outputs = out;                                   // (B,T,O)
    float* hidden  = out + (size_t)BB * TT * OO;            // (T+1,B,H)
    float* tcr     = out + (size_t)BB * TT * OO + (size_t)(TT + 1) * BB * HH;

    float* partials = (float*)d_ws;                         // [128], fully written

    rnn_main<<<dim3(BB), dim3(NTHREADS), 0, stream>>>(
        x, h0, W_rec, W_in, brec, bin, hidden, partials);
    rnn_out<<<dim3((BB * TT) / 4), dim3(256), 0, stream>>>(hidden, W_out, outputs);
    rnn_tcr<<<dim3(1), dim3(128), 0, stream>>>(partials, tcr);
}

// Round 16
// 1321.258 us; speedup vs baseline: 8.0354x; 8.0354x over previous
//
#include <hip/hip_runtime.h>
#include <math.h>

// leaky_current_RNN: B=128, T=512, I=4, H=512, O=3, alpha=0.5, n_reg=256.
// R16 = R10/R11 base (4-block groups, 2 cohorts, agent-scope (value|tag) u64
// exchange, pk_fma matvec, bar_lds) + three fixes from the revised model
// (R15 showed regs/SIMD pool = 512; pk_fma = 4cyc; VOP3P reads AGPRs free):
//  1. 4 independent acc chains (16 k each) -- kill 64-deep pk dependency.
//  2. Ring-of-4 staggered cross-cohort poll loads issued inside the matvec
//     (one per 16-k chunk) -- detection at issue-spacing, not serial RTT;
//     acquire checks oldest->newest, serial R5 loop fallback.
//  3. Finalize A on waves 0-1, finalize B on waves 2-3 (load balance).

#define BB 128
#define TT 512
#define II 4
#define HH 512
#define OO 3
#define NREG_ 256

#define NTHREADS 512
#define MEMBERS 4
#define NGROUPS 64
#define NBLOCKS (NGROUPS * MEMBERS)
#define STRIDE ((size_t)NGROUPS * HH)

#define WS_PART  (2 * 2 * NGROUPS * HH * 8)

typedef unsigned long long u64;
typedef unsigned int u32;
typedef __attribute__((ext_vector_type(2))) float f32x2;

__device__ __forceinline__ u64 aload(const u64* p) {
    return __hip_atomic_load(p, __ATOMIC_RELAXED, __HIP_MEMORY_SCOPE_AGENT);
}
__device__ __forceinline__ void astore(u64* p, u64 v) {
    __hip_atomic_store(p, v, __ATOMIC_RELAXED, __HIP_MEMORY_SCOPE_AGENT);
}
__device__ __forceinline__ float fast_tanh(float x) {
    float ax = fabsf(x);
    float e  = __expf(2.0f * ax);
    float r  = 1.0f - 2.0f * __builtin_amdgcn_rcpf(e + 1.0f);
    return copysignf(r, x);
}
__device__ __forceinline__ void bar_lds() {
    asm volatile("s_waitcnt lgkmcnt(0)" ::: "memory");
    __builtin_amdgcn_sched_barrier(0);
    __builtin_amdgcn_s_barrier();
    __builtin_amdgcn_sched_barrier(0);
}

#define R16X(M) M(0) M(1) M(2) M(3) M(4) M(5) M(6) M(7) \
                M(8) M(9) M(10) M(11) M(12) M(13) M(14) M(15)

// Weight pairs: w.x = W[k][memb*128+lane], w.y = W[k][memb*128+64+lane]
#define WLD(Q) \
    f32x2 w##Q##a, w##Q##b, w##Q##c, w##Q##d; \
    w##Q##a.x = Wp[(size_t)(4*Q+0)*HH]; w##Q##a.y = Wp[(size_t)(4*Q+0)*HH+64]; \
    w##Q##b.x = Wp[(size_t)(4*Q+1)*HH]; w##Q##b.y = Wp[(size_t)(4*Q+1)*HH+64]; \
    w##Q##c.x = Wp[(size_t)(4*Q+2)*HH]; w##Q##c.y = Wp[(size_t)(4*Q+2)*HH+64]; \
    w##Q##d.x = Wp[(size_t)(4*Q+3)*HH]; w##Q##d.y = Wp[(size_t)(4*Q+3)*HH+64];

#define KST(K, W, ACC) { \
    u32 s_ = __builtin_amdgcn_readlane(__float_as_uint(ar), (K)); \
    u64 ss = (u64)s_; \
    asm("v_pk_fma_f32 %0, %1, %2, %0 op_sel_hi:[0,1,1]" \
        : "+v"(ACC) : "s"(ss), "v"(W)); }

#define MVQ(Q, ACC) KST(4*Q+0, w##Q##a, ACC) KST(4*Q+1, w##Q##b, ACC) \
                    KST(4*Q+2, w##Q##c, ACC) KST(4*Q+3, w##Q##d, ACC)

// Matvec with 4 acc chains and a ring-issue after each 16-k chunk.
#define MATVEC(RING0, RING1, RING2, RING3, RP) \
    f32x2 acc0 = {0.f,0.f}, acc1 = {0.f,0.f}, acc2 = {0.f,0.f}, acc3 = {0.f,0.f}; \
    MVQ(0, acc0) MVQ(1, acc0) MVQ(2, acc0) MVQ(3, acc0)   RING0 = aload(RP); \
    MVQ(4, acc1) MVQ(5, acc1) MVQ(6, acc1) MVQ(7, acc1)   RING1 = aload(RP); \
    MVQ(8, acc2) MVQ(9, acc2) MVQ(10, acc2) MVQ(11, acc2) RING2 = aload(RP); \
    MVQ(12, acc3) MVQ(13, acc3) MVQ(14, acc3) MVQ(15, acc3) RING3 = aload(RP); \
    f32x2 acc = (acc0 + acc1) + (acc2 + acc3);

// Acquire: check ring oldest->newest (oldest already returned => no wait),
// serial R5 fallback loop if none match.
#define ACQ(R0, R1, R2, R3, P, TAGC, AR) { \
    u64 uu_; bool got_ = false; \
    if      (__all((u32)((R0) >> 32) == (TAGC))) { uu_ = (R0); got_ = true; } \
    else if (__all((u32)((R1) >> 32) == (TAGC))) { uu_ = (R1); got_ = true; } \
    else if (__all((u32)((R2) >> 32) == (TAGC))) { uu_ = (R2); got_ = true; } \
    else if (__all((u32)((R3) >> 32) == (TAGC))) { uu_ = (R3); got_ = true; } \
    if (!got_) { \
        for (;;) { uu_ = aload(P); \
                   if (__all((u32)(uu_ >> 32) == (TAGC))) break; } \
    } \
    AR = __uint_as_float((u32)uu_); }

// adat index: ((coh*2 + slot)*NGROUPS + g)*HH + col ; word = (tanh(h) | tag)
__global__ __launch_bounds__(NTHREADS) __attribute__((amdgpu_waves_per_eu(2, 2)))
void rnn_main(const float* __restrict__ x,
              const float* __restrict__ h0,
              const float* __restrict__ W_rec,
              const float* __restrict__ W_in,
              const float* __restrict__ bias_rec,
              const float* __restrict__ bias_in,
              float* __restrict__ hidden,
              u64* __restrict__ adat,
              float* __restrict__ partials)
{
    const int tid  = threadIdx.x;
    const int bid  = blockIdx.x;
    const int xcd  = bid & 7;
    const int onx  = bid >> 3;
    const int memb = onx & (MEMBERS - 1);
    const int g    = xcd * 8 + (onx >> 2);
    const int rA   = g;
    const int rB   = 64 + g;
    const int wid  = tid >> 6;
    const int lane = tid & 63;

    __shared__ float sc_s[2][128][9];
    __shared__ float xbuf[2][TT * II];
    __shared__ float win_s[II][128];
    __shared__ float ub_s[128];
    __shared__ float red_s[NTHREADS / 64];

    for (int idx = tid; idx < TT * II; idx += NTHREADS) {
        xbuf[0][idx] = x[(size_t)rA * (TT * II) + idx];
        xbuf[1][idx] = x[(size_t)rB * (TT * II) + idx];
    }
    if (tid < II * 128) {
        int i = tid >> 7, jj = tid & 127;
        win_s[i][jj] = W_in[i * HH + memb * 128 + jj];
    }
    if (tid < 128) {
        ub_s[tid] = bias_rec[memb * 128 + tid] + bias_in[memb * 128 + tid];
    }

    const float* Wp = W_rec + (size_t)(wid * 64) * HH + memb * 128 + lane;
    R16X(WLD)

    // ---- prologue: A state on waves 0-1, B state on waves 2-3 ----
    const int fj  = tid & 127;
    const int fjg = memb * 128 + fj;
    float hprevA = 0.0f, zprevA = 0.0f;
    float hprevB = 0.0f, zprevB = 0.0f;
    float racc = 0.0f;
    if (tid < 128) {
        hprevA = h0[(size_t)rA * HH + fjg];
        u64 pA = (u64)__float_as_uint(fast_tanh(hprevA)) | ((u64)1u << 32);
        astore(&adat[((size_t)(0 * 2 + 0) * NGROUPS + g) * HH + fjg], pA);
        hidden[(size_t)rA * HH + fjg] = hprevA;
    } else if (tid < 256) {
        hprevB = h0[(size_t)rB * HH + fjg];
        u64 pB = (u64)__float_as_uint(fast_tanh(hprevB)) | ((u64)1u << 32);
        astore(&adat[((size_t)(1 * 2 + 0) * NGROUPS + g) * HH + fjg], pB);
        hidden[(size_t)rB * HH + fjg] = hprevB;
    }

    const size_t kidx = (size_t)wid * 64 + lane;
    const u64* ppA = adat + ((size_t)(0 * 2 + 0) * NGROUPS + g) * HH + kidx;
    const u64* ppB = adat + ((size_t)(1 * 2 + 0) * NGROUPS + g) * HH + kidx;

    // seed rings for t=0 (slot 0)
    u64 rA0 = aload(ppA), rA1 = aload(ppA), rA2 = aload(ppA), rA3 = aload(ppA);
    u64 rB0 = aload(ppB), rB1 = aload(ppB), rB2 = aload(ppB), rB3 = aload(ppB);

#pragma unroll 1
    for (int t = 0; t < TT; ++t) {
        const int slot  = t & 1;
        const int slot2 = (t + 1) & 1;
        const u32 tagc  = (u32)(t + 1);
        const u64 tagp  = ((u64)(t + 2) << 32);
        const u64* pA_cur  = ppA + (size_t)slot  * STRIDE;
        const u64* pB_cur  = ppB + (size_t)slot  * STRIDE;
        const u64* pA_next = ppA + (size_t)slot2 * STRIDE;

        // ===== Region 1: finalize B(t-1) [waves 2-3]; acquire+matvec A =====
        if (t > 0 && tid >= 128 && tid < 256) {
            const int s = t - 1;             // B's step index
            const int sslot = s & 1;
            float q0 = sc_s[sslot][fj][0], q1 = sc_s[sslot][fj][1];
            float q2 = sc_s[sslot][fj][2], q3 = sc_s[sslot][fj][3];
            float q4 = sc_s[sslot][fj][4], q5 = sc_s[sslot][fj][5];
            float q6 = sc_s[sslot][fj][6], q7 = sc_s[sslot][fj][7];
            float z = ((q0 + q1) + (q2 + q3)) + ((q4 + q5) + (q6 + q7));
            z += ub_s[fj];
            const float* xr = &xbuf[1][s * II];
            z = fmaf(xr[0], win_s[0][fj], z);
            z = fmaf(xr[1], win_s[1][fj], z);
            z = fmaf(xr[2], win_s[2][fj], z);
            z = fmaf(xr[3], win_s[3][fj], z);
            float hn = 0.5f * hprevB + 0.5f * z;
            u64 pv = (u64)__float_as_uint(fast_tanh(hn)) | ((u64)(s + 2) << 32);
            astore(&adat[((size_t)(1 * 2 + ((s + 1) & 1)) * NGROUPS + g) * HH + fjg], pv);
            hidden[(size_t)(s + 1) * BB * HH + (size_t)rB * HH + fjg] = hn;
            if (fjg < NREG_) {
                float d1 = hn - hprevB;
                racc = fmaf(d1, d1, racc);
                if (s > 0) { float d2 = z - zprevB; racc = fmaf(d2, d2, racc); }
                zprevB = z;
            }
            hprevB = hn;
        }
        {
            float ar;
            ACQ(rA0, rA1, rA2, rA3, pA_cur, tagc, ar)
            MATVEC(rB0, rB1, rB2, rB3, pB_cur)
            sc_s[slot][lane][wid]      = acc.x;
            sc_s[slot][lane + 64][wid] = acc.y;
        }
        bar_lds();

        // ===== Region 2: finalize A(t) [waves 0-1]; acquire+matvec B =====
        if (tid < 128) {
            float q0 = sc_s[slot][fj][0], q1 = sc_s[slot][fj][1];
            float q2 = sc_s[slot][fj][2], q3 = sc_s[slot][fj][3];
            float q4 = sc_s[slot][fj][4], q5 = sc_s[slot][fj][5];
            float q6 = sc_s[slot][fj][6], q7 = sc_s[slot][fj][7];
            float z = ((q0 + q1) + (q2 + q3)) + ((q4 + q5) + (q6 + q7));
            z += ub_s[fj];
            const float* xr = &xbuf[0][t * II];
            z = fmaf(xr[0], win_s[0][fj], z);
            z = fmaf(xr[1], win_s[1][fj], z);
            z = fmaf(xr[2], win_s[2][fj], z);
            z = fmaf(xr[3], win_s[3][fj], z);
            float hn = 0.5f * hprevA + 0.5f * z;
            u64 pv = (u64)__float_as_uint(fast_tanh(hn)) | tagp;
            astore(&adat[((size_t)(0 * 2 + slot2) * NGROUPS + g) * HH + fjg], pv);
            hidden[(size_t)(t + 1) * BB * HH + (size_t)rA * HH + fjg] = hn;
            if (fjg < NREG_) {
                float d1 = hn - hprevA;
                racc = fmaf(d1, d1, racc);
                if (t > 0) { float d2 = z - zprevA; racc = fmaf(d2, d2, racc); }
                zprevA = z;
            }
            hprevA = hn;
        }
        {
            float ar;
            ACQ(rB0, rB1, rB2, rB3, pB_cur, tagc, ar)
            MATVEC(rA0, rA1, rA2, rA3, pA_next)
            sc_s[slot][lane][wid]      = acc.x;   // B uses same slot buffer idx 1
            sc_s[slot][lane + 64][wid] = acc.y;
        }
        bar_lds();
    }

    // ---- post-loop: finalize B(511) ----
    if (tid >= 128 && tid < 256) {
        const int s = TT - 1;
        const int sslot = s & 1;
        float q0 = sc_s[sslot][fj][0], q1 = sc_s[sslot][fj][1];
        float q2 = sc_s[sslot][fj][2], q3 = sc_s[sslot][fj][3];
        float q4 = sc_s[sslot][fj][4], q5 = sc_s[sslot][fj][5];
        float q6 = sc_s[sslot][fj][6], q7 = sc_s[sslot][fj][7];
        float z = ((q0 + q1) + (q2 + q3)) + ((q4 + q5) + (q6 + q7));
        z += ub_s[fj];
        const float* xr = &xbuf[1][s * II];
        z = fmaf(xr[0], win_s[0][fj], z);
        z = fmaf(xr[1], win_s[1][fj], z);
        z = fmaf(xr[2], win_s[2][fj], z);
        z = fmaf(xr[3], win_s[3][fj], z);
        float hn = 0.5f * hprevB + 0.5f * z;
        hidden[(size_t)(s + 1) * BB * HH + (size_t)rB * HH + fjg] = hn;
        if (fjg < NREG_) {
            float d1 = hn - hprevB;
            racc = fmaf(d1, d1, racc);
            if (s > 0) { float d2 = z - zprevB; racc = fmaf(d2, d2, racc); }
        }
    }

    // ---- block-reduce reg partial (stored by ROLE for determinism) ----
    for (int off = 32; off; off >>= 1) racc += __shfl_down(racc, off);
    if ((tid & 63) == 0) red_s[tid >> 6] = racc;
    __syncthreads();
    if (tid == 0) {
        float s = 0.0f;
        for (int i = 0; i < NTHREADS / 64; ++i) s += red_s[i];
        partials[g * MEMBERS + memb] = s;
    }
}

// WAIT: Region-1/Region-2 both write sc_s[slot] -- cohorts must use distinct
// buffers. Cohort A uses sc_s[0-indexed-by... see launch note below.
// (A writes/reads sc_s[slot], B writes/reads sc_s[slot] in a DIFFERENT
// region separated by barriers on both sides -- A's finalize (region 2)
// reads sc_s[slot] before B's matvec (also region 2) could... they are in
// the SAME region. B's matvec writes sc_s[slot] while A's finalize reads
// sc_s[slot]: RACE. Fixed by giving B the other buffer: B uses sc_s[slot^1].
// The definition below is the corrected kernel; the one above is dead code.

__global__ __launch_bounds__(256)
void rnn_out(const float* __restrict__ hidden,
             const float* __restrict__ W_out,
             float* __restrict__ outputs)
{
    __shared__ float wout_s[HH * OO];
    const int tid = threadIdx.x;
    for (int i = tid; i < HH * OO; i += 256) wout_s[i] = W_out[i];
    __syncthreads();

    const int gid  = blockIdx.x * 4 + (tid >> 6);
    const int lane = tid & 63;
    const int b = gid >> 9;
    const int t = gid & (TT - 1);
    const float* hp = hidden + (size_t)(t + 1) * BB * HH + (size_t)b * HH;

    float o0 = 0.0f, o1 = 0.0f, o2 = 0.0f;
#pragma unroll
    for (int q = 0; q < 8; ++q) {
        int k = lane + 64 * q;
        float hv = hp[k];
        o0 = fmaf(hv, wout_s[k * 3 + 0], o0);
        o1 = fmaf(hv, wout_s[k * 3 + 1], o1);
        o2 = fmaf(hv, wout_s[k * 3 + 2], o2);
    }
    for (int off = 32; off; off >>= 1) {
        o0 += __shfl_down(o0, off);
        o1 += __shfl_down(o1, off);
        o2 += __shfl_down(o2, off);
    }
    if (lane == 0) {
        float* op = outputs + (size_t)(b * TT + t) * OO;
        op[0] = o0; op[1] = o1; op[2] = o2;
    }
}

__global__ __launch_bounds__(256)
void rnn_tcr(const float* __restrict__ partials, float* __restrict__ tcr)
{
    __shared__ float red[4];
    const int tid = threadIdx.x;
    float v = partials[tid];
    for (int off = 32; off; off >>= 1) v += __shfl_down(v, off);
    if ((tid & 63) == 0) red[tid >> 6] = v;
    __syncthreads();
    if (tid == 0) {
        float s = red[0] + red[1] + red[2] + red[3];
        *tcr = s * (1.0f / ((float)TT * (float)BB * (float)NREG_));
    }
}

// Corrected main kernel: B uses sc buffer index (slot^1) so A-finalize and
// B-matvec (same region) touch different buffers.
__global__ __launch_bounds__(NTHREADS) __attribute__((amdgpu_waves_per_eu(2, 2)))
void rnn_main2(const float* __restrict__ x,
               const float* __restrict__ h0,
               const float* __restrict__ W_rec,
               const float* __restrict__ W_in,
               const float* __restrict__ bias_rec,
               const float* __restrict__ bias_in,
               float* __restrict__ hidden,
               u64* __restrict__ adat,
               float* __restrict__ partials)
{
    const int tid  = threadIdx.x;
    const int bid  = blockIdx.x;
    const int xcd  = bid & 7;
    const int onx  = bid >> 3;
    const int memb = onx & (MEMBERS - 1);
    const int g    = xcd * 8 + (onx >> 2);
    const int rA   = g;
    const int rB   = 64 + g;
    const int wid  = tid >> 6;
    const int lane = tid & 63;

    __shared__ float sc_s[2][128][9];
    __shared__ float xbuf[2][TT * II];
    __shared__ float win_s[II][128];
    __shared__ float ub_s[128];
    __shared__ float red_s[NTHREADS / 64];

    for (int idx = tid; idx < TT * II; idx += NTHREADS) {
        xbuf[0][idx] = x[(size_t)rA * (TT * II) + idx];
        xbuf[1][idx] = x[(size_t)rB * (TT * II) + idx];
    }
    if (tid < II * 128) {
        int i = tid >> 7, jj = tid & 127;
        win_s[i][jj] = W_in[i * HH + memb * 128 + jj];
    }
    if (tid < 128) {
        ub_s[tid] = bias_rec[memb * 128 + tid] + bias_in[memb * 128 + tid];
    }

    const float* Wp = W_rec + (size_t)(wid * 64) * HH + memb * 128 + lane;
    R16X(WLD)

    const int fj  = tid & 127;
    const int fjg = memb * 128 + fj;
    float hprevA = 0.0f, zprevA = 0.0f;
    float hprevB = 0.0f, zprevB = 0.0f;
    float racc = 0.0f;
    if (tid < 128) {
        hprevA = h0[(size_t)rA * HH + fjg];
        u64 pA = (u64)__float_as_uint(fast_tanh(hprevA)) | ((u64)1u << 32);
        astore(&adat[((size_t)(0 * 2 + 0) * NGROUPS + g) * HH + fjg], pA);
        hidden[(size_t)rA * HH + fjg] = hprevA;
    } else if (tid < 256) {
        hprevB = h0[(size_t)rB * HH + fjg];
        u64 pB = (u64)__float_as_uint(fast_tanh(hprevB)) | ((u64)1u << 32);
        astore(&adat[((size_t)(1 * 2 + 0) * NGROUPS + g) * HH + fjg], pB);
        hidden[(size_t)rB * HH + fjg] = hprevB;
    }

    const size_t kidx = (size_t)wid * 64 + lane;
    const u64* ppA = adat + ((size_t)(0 * 2 + 0) * NGROUPS + g) * HH + kidx;
    const u64* ppB = adat + ((size_t)(1 * 2 + 0) * NGROUPS + g) * HH + kidx;

    u64 rA0 = aload(ppA), rA1 = aload(ppA), rA2 = aload(ppA), rA3 = aload(ppA);
    u64 rB0 = aload(ppB), rB1 = aload(ppB), rB2 = aload(ppB), rB3 = aload(ppB);

#pragma unroll 1
    for (int t = 0; t < TT; ++t) {
        const int slot  = t & 1;
        const int slot2 = (t + 1) & 1;
        const u32 tagc  = (u32)(t + 1);
        const u64 tagp  = ((u64)(t + 2) << 32);
        const u64* pA_cur  = ppA + (size_t)slot  * STRIDE;
        const u64* pB_cur  = ppB + (size_t)slot  * STRIDE;
        const u64* pA_next = ppA + (size_t)slot2 * STRIDE;

        // ===== Region 1: finalize B(t-1) [waves 2-3]; acquire+matvec A =====
        // B's sc buffer for step s is sc_s[(s&1)^1].
        if (t > 0 && tid >= 128 && tid < 256) {
            const int s = t - 1;
            const int sbuf = (s & 1) ^ 1;
            float q0 = sc_s[sbuf][fj][0], q1 = sc_s[sbuf][fj][1];
            float q2 = sc_s[sbuf][fj][2], q3 = sc_s[sbuf][fj][3];
            float q4 = sc_s[sbuf][fj][4], q5 = sc_s[sbuf][fj][5];
            float q6 = sc_s[sbuf][fj][6], q7 = sc_s[sbuf][fj][7];
            float z = ((q0 + q1) + (q2 + q3)) + ((q4 + q5) + (q6 + q7));
            z += ub_s[fj];
            const float* xr = &xbuf[1][s * II];
            z = fmaf(xr[0], win_s[0][fj], z);
            z = fmaf(xr[1], win_s[1][fj], z);
            z = fmaf(xr[2], win_s[2][fj], z);
            z = fmaf(xr[3], win_s[3][fj], z);
            float hn = 0.5f * hprevB + 0.5f * z;
            u64 pv = (u64)__float_as_uint(fast_tanh(hn)) | ((u64)(s + 2) << 32);
            astore(&adat[((size_t)(1 * 2 + ((s + 1) & 1)) * NGROUPS + g) * HH + fjg], pv);
            hidden[(size_t)(s + 1) * BB * HH + (size_t)rB * HH + fjg] = hn;
            if (fjg < NREG_) {
                float d1 = hn - hprevB;
                racc = fmaf(d1, d1, racc);
                if (s > 0) { float d2 = z - zprevB; racc = fmaf(d2, d2, racc); }
                zprevB = z;
            }
            hprevB = hn;
        }
        {
            float ar;
            ACQ(rA0, rA1, rA2, rA3, pA_cur, tagc, ar)
            MATVEC(rB0, rB1, rB2, rB3, pB_cur)
            sc_s[slot][lane][wid]      = acc.x;
            sc_s[slot][lane + 64][wid] = acc.y;
        }
        bar_lds();

        // ===== Region 2: finalize A(t) [waves 0-1]; acquire+matvec B =====
        if (tid < 128) {
            float q0 = sc_s[slot][fj][0], q1 = sc_s[slot][fj][1];
            float q2 = sc_s[slot][fj][2], q3 = sc_s[slot][fj][3];
            float q4 = sc_s[slot][fj][4], q5 = sc_s[slot][fj][5];
            float q6 = sc_s[slot][fj][6], q7 = sc_s[slot][fj][7];
            float z = ((q0 + q1) + (q2 + q3)) + ((q4 + q5) + (q6 + q7));
            z += ub_s[fj];
            const float* xr = &xbuf[0][t * II];
            z = fmaf(xr[0], win_s[0][fj], z);
            z = fmaf(xr[1], win_s[1][fj], z);
            z = fmaf(xr[2], win_s[2][fj], z);
            z = fmaf(xr[3], win_s[3][fj], z);
            float hn = 0.5f * hprevA + 0.5f * z;
            u64 pv = (u64)__float_as_uint(fast_tanh(hn)) | tagp;
            astore(&adat[((size_t)(0 * 2 + slot2) * NGROUPS + g) * HH + fjg], pv);
            hidden[(size_t)(t + 1) * BB * HH + (size_t)rA * HH + fjg] = hn;
            if (fjg < NREG_) {
                float d1 = hn - hprevA;
                racc = fmaf(d1, d1, racc);
                if (t > 0) { float d2 = z - zprevA; racc = fmaf(d2, d2, racc); }
                zprevA = z;
            }
            hprevA = hn;
        }
        {
            float ar;
            ACQ(rB0, rB1, rB2, rB3, pB_cur, tagc, ar)
            MATVEC(rA0, rA1, rA2, rA3, pA_next)
            sc_s[slot2][lane][wid]      = acc.x;   // B buffer = slot^1
            sc_s[slot2][lane + 64][wid] = acc.y;
        }
        bar_lds();
    }

    // ---- post-loop: finalize B(511) (sc buffer = (511&1)^1 = 0) ----
    if (tid >= 128 && tid < 256) {
        const int s = TT - 1;
        const int sbuf = (s & 1) ^ 1;
        float q0 = sc_s[sbuf][fj][0], q1 = sc_s[sbuf][fj][1];
        float q2 = sc_s[sbuf][fj][2], q3 = sc_s[sbuf][fj][3];
        float q4 = sc_s[sbuf][fj][4], q5 = sc_s[sbuf][fj][5];
        float q6 = sc_s[sbuf][fj][6], q7 = sc_s[sbuf][fj][7];
        float z = ((q0 + q1) + (q2 + q3)) + ((q4 + q5) + (q6 + q7));
        z += ub_s[fj];
        const float* xr = &xbuf[1][s * II];
        z = fmaf(xr[0], win_s[0][fj], z);
        z = fmaf(xr[1], win_s[1][fj], z);
        z = fmaf(xr[2], win_s[2][fj], z);
        z = fmaf(xr[3], win_s[3][fj], z);
        float hn = 0.5f * hprevB + 0.5f * z;
        hidden[(size_t)(s + 1) * BB * HH + (size_t)rB * HH + fjg] = hn;
        if (fjg < NREG_) {
            float d1 = hn - hprevB;
            racc = fmaf(d1, d1, racc);
            if (s > 0) { float d2 = z - zprevB; racc = fmaf(d2, d2, racc); }
        }
    }

    for (int off = 32; off; off >>= 1) racc += __shfl_down(racc, off);
    if ((tid & 63) == 0) red_s[tid >> 6] = racc;
    __syncthreads();
    if (tid == 0) {
        float s = 0.0f;
        for (int i = 0; i < NTHREADS / 64; ++i) s += red_s[i];
        partials[g * MEMBERS + memb] = s;
    }
}

extern "C" void kernel_launch(void* const* d_in, const int* in_sizes, int n_in,
                              void* d_out, int out_size, void* d_ws, size_t ws_size,
                              hipStream_t stream)
{
    (void)in_sizes; (void)n_in; (void)out_size; (void)ws_size;

    const float* x     = (const float*)d_in[0];
    const float* h0    = (const float*)d_in[1];
    const float* W_rec = (const float*)d_in[2];
    const float* W_in  = (const float*)d_in[3];
    const float* W_out = (const float*)d_in[4];
    const float* brec  = (const float*)d_in[5];
    const float* bin   = (const float*)d_in[6];

    float* out     = (float*)d_out;
    float* outputs = out;
    float* hidden  = out + (size_t)BB * TT * OO;
    float* tcr     = out + (size_t)BB * TT * OO + (size_t)(TT + 1) * BB * HH;

    u64*   adat     = (u64*)d_ws;
    float* partials = (float*)((char*)d_ws + WS_PART);

    (void)hipMemsetAsync(d_ws, 0, WS_PART, stream);

    void* args[] = { (void*)&x, (void*)&h0, (void*)&W_rec, (void*)&W_in,
                     (void*)&brec, (void*)&bin, (void*)&hidden,
                     (void*)&adat, (void*)&partials };
    (void)hipLaunchCooperativeKernel((const void*)rnn_main2,
                                     dim3(NBLOCKS), dim3(NTHREADS),
                                     args, 0, stream);

    rnn_out<<<dim3((BB * TT) / 4), dim3(256), 0, stream>>>(hidden, W_out, outputs);
    rnn_tcr<<<dim3(1), dim3(128), 0, stream>>>(partials, tcr);
}

// Round 17
// 1190.168 us; speedup vs baseline: 8.9205x; 1.1101x over previous
//
#include <hip/hip_runtime.h>
#include <math.h>

// leaky_current_RNN: B=128, T=512, I=4, H=512, O=3, alpha=0.5, n_reg=256.
// R17 = R10 (proven 987us) + ONE change: finalize distributed across all 8
// waves (col c owned by wave c>>4, lane c&15) instead of waves 0-1 only.
// R16 postmortem: its finalize-skew raced on sc_s (absmax 0.0039->0.022);
// reverted. R10's residual critical path includes 2-wave finalize that all
// other waves wait on at the next barrier; spreading it 8-ways removes
// ~7/8 of that serialization and issues publishes from all 4 SIMDs.

#define BB 128
#define TT 512
#define II 4
#define HH 512
#define OO 3
#define NREG_ 256

#define NTHREADS 512
#define MEMBERS 4
#define NGROUPS 64
#define NBLOCKS (NGROUPS * MEMBERS)

// d_ws layout (bytes): adat u64[2 coh][2 slot][64 g][512 col] = 1 MB
#define WS_PART  (2 * 2 * NGROUPS * HH * 8)

typedef unsigned long long u64;
typedef unsigned int u32;
typedef __attribute__((ext_vector_type(2))) float f32x2;

__device__ __forceinline__ u64 aload(const u64* p) {
    return __hip_atomic_load(p, __ATOMIC_RELAXED, __HIP_MEMORY_SCOPE_AGENT);
}
__device__ __forceinline__ void astore(u64* p, u64 v) {
    __hip_atomic_store(p, v, __ATOMIC_RELAXED, __HIP_MEMORY_SCOPE_AGENT);
}
__device__ __forceinline__ float fast_tanh(float x) {
    float ax = fabsf(x);
    float e  = __expf(2.0f * ax);
    float r  = 1.0f - 2.0f * __builtin_amdgcn_rcpf(e + 1.0f);
    return copysignf(r, x);
}

#define R16X(M) M(0) M(1) M(2) M(3) M(4) M(5) M(6) M(7) \
                M(8) M(9) M(10) M(11) M(12) M(13) M(14) M(15)

// Weight pairs: w.x = W[k][memb*128+lane], w.y = W[k][memb*128+64+lane]
#define WLD(Q) \
    f32x2 w##Q##a, w##Q##b, w##Q##c, w##Q##d; \
    w##Q##a.x = Wp[(size_t)(4*Q+0)*HH]; w##Q##a.y = Wp[(size_t)(4*Q+0)*HH+64]; \
    w##Q##b.x = Wp[(size_t)(4*Q+1)*HH]; w##Q##b.y = Wp[(size_t)(4*Q+1)*HH+64]; \
    w##Q##c.x = Wp[(size_t)(4*Q+2)*HH]; w##Q##c.y = Wp[(size_t)(4*Q+2)*HH+64]; \
    w##Q##d.x = Wp[(size_t)(4*Q+3)*HH]; w##Q##d.y = Wp[(size_t)(4*Q+3)*HH+64];

// acc = (colA, colB) for ONE row: row-scalar broadcast via op_sel_hi[0]=0.
#define KSTEP(K, W) { \
    u32 s_ = __builtin_amdgcn_readlane(__float_as_uint(ar), (K)); \
    u64 ss = (u64)s_; \
    asm("v_pk_fma_f32 %0, %1, %2, %0 op_sel_hi:[0,1,1]" \
        : "+v"(acc) : "s"(ss), "v"(W)); }

#define MV(Q) KSTEP(4*Q+0, w##Q##a) KSTEP(4*Q+1, w##Q##b) \
              KSTEP(4*Q+2, w##Q##c) KSTEP(4*Q+3, w##Q##d)

// adat index: ((coh*2 + slot)*NGROUPS + g)*HH + col ; word = (tanh(h) | tag)
__global__ __launch_bounds__(NTHREADS) __attribute__((amdgpu_waves_per_eu(2, 2)))
void rnn_main(const float* __restrict__ x,
              const float* __restrict__ h0,
              const float* __restrict__ W_rec,
              const float* __restrict__ W_in,
              const float* __restrict__ bias_rec,
              const float* __restrict__ bias_in,
              float* __restrict__ hidden,      // (T+1, B, H) region of d_out
              u64* __restrict__ adat,          // exchange buffer in d_ws
              float* __restrict__ partials)
{
    const int tid  = threadIdx.x;
    const int bid  = blockIdx.x;
    const int xcd  = bid & 7;
    const int onx  = bid >> 3;
    const int memb = onx & (MEMBERS - 1);
    const int g    = xcd * 8 + (onx >> 2);    // 0..63
    const int rA   = g;                       // cohort A row
    const int rB   = 64 + g;                  // cohort B row
    const int wid  = tid >> 6;                // k-window [64*wid, 64*wid+64)
    const int lane = tid & 63;

    __shared__ float sc_s[2][128][9];         // per-cohort split-k partials
    __shared__ float xbuf[2][TT * II];        // x rows (A, B)
    __shared__ float win_s[II][128];
    __shared__ float ub_s[128];
    __shared__ float red_s[NTHREADS / 64];

    // ---- one-time staging ----
    for (int idx = tid; idx < TT * II; idx += NTHREADS) {
        xbuf[0][idx] = x[(size_t)rA * (TT * II) + idx];
        xbuf[1][idx] = x[(size_t)rB * (TT * II) + idx];
    }
    if (tid < II * 128) {
        int i = tid >> 7, jj = tid & 127;
        win_s[i][jj] = W_in[i * HH + memb * 128 + jj];
    }
    if (tid < 128) {
        ub_s[tid] = bias_rec[memb * 128 + tid] + bias_in[memb * 128 + tid];
    }

    // ---- W_rec slice into registers as float2 (colA,colB) pairs ----
    const float* Wp = W_rec + (size_t)(wid * 64) * HH + memb * 128 + lane;
    R16X(WLD)

    // ---- finalize ownership: col fcol = wid*16 + lane, for lane < 16 ----
    const int fcol = wid * 16 + lane;         // 0..127 (one per owner thread)
    const int fjg  = memb * 128 + fcol;
    float hprevA = 0.0f, zprevA = 0.0f;
    float hprevB = 0.0f, zprevB = 0.0f;
    float racc = 0.0f;
    if (lane < 16) {
        hprevA = h0[(size_t)rA * HH + fjg];
        hprevB = h0[(size_t)rB * HH + fjg];
        u64 pA = (u64)__float_as_uint(fast_tanh(hprevA)) | ((u64)1u << 32);
        u64 pB = (u64)__float_as_uint(fast_tanh(hprevB)) | ((u64)1u << 32);
        astore(&adat[((size_t)(0 * 2 + 0) * NGROUPS + g) * HH + fjg], pA);
        astore(&adat[((size_t)(1 * 2 + 0) * NGROUPS + g) * HH + fjg], pB);
        hidden[(size_t)rA * HH + fjg] = hprevA;
        hidden[(size_t)rB * HH + fjg] = hprevB;
    }

#pragma unroll 1
    for (int t = 0; t < TT; ++t) {
        const int slot  = t & 1;
        const int slot2 = (t + 1) & 1;
        const u32 tagc  = (u32)(t + 1);
        const u64 tagp  = ((u64)(t + 2) << 32);

        // ================= PHASE A =================
        {
            const u64* pp = adat + ((size_t)(0 * 2 + slot) * NGROUPS + g) * HH
                            + wid * 64 + lane;
            u64 u;
            for (;;) {
                u = aload(pp);
                if (__all((u32)(u >> 32) == tagc)) break;
            }
            float ar = __uint_as_float((u32)u);

            f32x2 acc = {0.0f, 0.0f};
            R16X(MV)
            sc_s[0][lane][wid]      = acc.x;
            sc_s[0][lane + 64][wid] = acc.y;
        }
        __syncthreads();
        if (lane < 16) {
            float q0 = sc_s[0][fcol][0], q1 = sc_s[0][fcol][1];
            float q2 = sc_s[0][fcol][2], q3 = sc_s[0][fcol][3];
            float q4 = sc_s[0][fcol][4], q5 = sc_s[0][fcol][5];
            float q6 = sc_s[0][fcol][6], q7 = sc_s[0][fcol][7];
            float z = ((q0 + q1) + (q2 + q3)) + ((q4 + q5) + (q6 + q7));
            z += ub_s[fcol];
            const float* xr = &xbuf[0][t * II];
            z = fmaf(xr[0], win_s[0][fcol], z);
            z = fmaf(xr[1], win_s[1][fcol], z);
            z = fmaf(xr[2], win_s[2][fcol], z);
            z = fmaf(xr[3], win_s[3][fcol], z);
            float hn = 0.5f * hprevA + 0.5f * z;
            u64 pv = (u64)__float_as_uint(fast_tanh(hn)) | tagp;
            astore(&adat[((size_t)(0 * 2 + slot2) * NGROUPS + g) * HH + fjg], pv);
            hidden[(size_t)(t + 1) * BB * HH + (size_t)rA * HH + fjg] = hn;
            if (fjg < NREG_) {
                float d1 = hn - hprevA;
                racc = fmaf(d1, d1, racc);
                if (t > 0) { float d2 = z - zprevA; racc = fmaf(d2, d2, racc); }
                zprevA = z;
            }
            hprevA = hn;
        }

        // ================= PHASE B =================
        {
            const u64* pp = adat + ((size_t)(1 * 2 + slot) * NGROUPS + g) * HH
                            + wid * 64 + lane;
            u64 u;
            for (;;) {
                u = aload(pp);
                if (__all((u32)(u >> 32) == tagc)) break;
            }
            float ar = __uint_as_float((u32)u);

            f32x2 acc = {0.0f, 0.0f};
            R16X(MV)
            sc_s[1][lane][wid]      = acc.x;
            sc_s[1][lane + 64][wid] = acc.y;
        }
        __syncthreads();
        if (lane < 16) {
            float q0 = sc_s[1][fcol][0], q1 = sc_s[1][fcol][1];
            float q2 = sc_s[1][fcol][2], q3 = sc_s[1][fcol][3];
            float q4 = sc_s[1][fcol][4], q5 = sc_s[1][fcol][5];
            float q6 = sc_s[1][fcol][6], q7 = sc_s[1][fcol][7];
            float z = ((q0 + q1) + (q2 + q3)) + ((q4 + q5) + (q6 + q7));
            z += ub_s[fcol];
            const float* xr = &xbuf[1][t * II];
            z = fmaf(xr[0], win_s[0][fcol], z);
            z = fmaf(xr[1], win_s[1][fcol], z);
            z = fmaf(xr[2], win_s[2][fcol], z);
            z = fmaf(xr[3], win_s[3][fcol], z);
            float hn = 0.5f * hprevB + 0.5f * z;
            u64 pv = (u64)__float_as_uint(fast_tanh(hn)) | tagp;
            astore(&adat[((size_t)(1 * 2 + slot2) * NGROUPS + g) * HH + fjg], pv);
            hidden[(size_t)(t + 1) * BB * HH + (size_t)rB * HH + fjg] = hn;
            if (fjg < NREG_) {
                float d1 = hn - hprevB;
                racc = fmaf(d1, d1, racc);
                if (t > 0) { float d2 = z - zprevB; racc = fmaf(d2, d2, racc); }
                zprevB = z;
            }
            hprevB = hn;
        }
    }

    // ---- block-reduce reg partial (stored by ROLE for determinism) ----
    for (int off = 32; off; off >>= 1) racc += __shfl_down(racc, off);
    if ((tid & 63) == 0) red_s[tid >> 6] = racc;
    __syncthreads();
    if (tid == 0) {
        float s = 0.0f;
        for (int i = 0; i < NTHREADS / 64; ++i) s += red_s[i];
        partials[g * MEMBERS + memb] = s;
    }
}

// outputs[b][t][:] = hidden[t+1][b][:] @ W_out   (one wave per (b,t))
__global__ __launch_bounds__(256)
void rnn_out(const float* __restrict__ hidden,
             const float* __restrict__ W_out,
             float* __restrict__ outputs)
{
    __shared__ float wout_s[HH * OO];
    const int tid = threadIdx.x;
    for (int i = tid; i < HH * OO; i += 256) wout_s[i] = W_out[i];
    __syncthreads();

    const int gid  = blockIdx.x * 4 + (tid >> 6);
    const int lane = tid & 63;
    const int b = gid >> 9;
    const int t = gid & (TT - 1);
    const float* hp = hidden + (size_t)(t + 1) * BB * HH + (size_t)b * HH;

    float o0 = 0.0f, o1 = 0.0f, o2 = 0.0f;
#pragma unroll
    for (int q = 0; q < 8; ++q) {
        int k = lane + 64 * q;
        float hv = hp[k];
        o0 = fmaf(hv, wout_s[k * 3 + 0], o0);
        o1 = fmaf(hv, wout_s[k * 3 + 1], o1);
        o2 = fmaf(hv, wout_s[k * 3 + 2], o2);
    }
    for (int off = 32; off; off >>= 1) {
        o0 += __shfl_down(o0, off);
        o1 += __shfl_down(o1, off);
        o2 += __shfl_down(o2, off);
    }
    if (lane == 0) {
        float* op = outputs + (size_t)(b * TT + t) * OO;
        op[0] = o0; op[1] = o1; op[2] = o2;
    }
}

__global__ __launch_bounds__(256)
void rnn_tcr(const float* __restrict__ partials, float* __restrict__ tcr)
{
    __shared__ float red[4];
    const int tid = threadIdx.x;
    float v = partials[tid];
    for (int off = 32; off; off >>= 1) v += __shfl_down(v, off);
    if ((tid & 63) == 0) red[tid >> 6] = v;
    __syncthreads();
    if (tid == 0) {
        float s = red[0] + red[1] + red[2] + red[3];
        *tcr = s * (1.0f / ((float)TT * (float)BB * (float)NREG_));
    }
}

extern "C" void kernel_launch(void* const* d_in, const int* in_sizes, int n_in,
                              void* d_out, int out_size, void* d_ws, size_t ws_size,
                              hipStream_t stream)
{
    (void)in_sizes; (void)n_in; (void)out_size; (void)ws_size;

    const float* x     = (const float*)d_in[0];
    const float* h0    = (const float*)d_in[1];
    const float* W_rec = (const float*)d_in[2];
    const float* W_in  = (const float*)d_in[3];
    const float* W_out = (const float*)d_in[4];
    const float* brec  = (const float*)d_in[5];
    const float* bin   = (const float*)d_in[6];

    float* out     = (float*)d_out;
    float* outputs = out;
    float* hidden  = out + (size_t)BB * TT * OO;
    float* tcr     = out + (size_t)BB * TT * OO + (size_t)(TT + 1) * BB * HH;

    u64*   adat     = (u64*)d_ws;
    float* partials = (float*)((char*)d_ws + WS_PART);

    // zero exchange-buffer tags every call (graph replays reuse d_ws)
    (void)hipMemsetAsync(d_ws, 0, WS_PART, stream);

    void* args[] = { (void*)&x, (void*)&h0, (void*)&W_rec, (void*)&W_in,
                     (void*)&brec, (void*)&bin, (void*)&hidden,
                     (void*)&adat, (void*)&partials };
    (void)hipLaunchCooperativeKernel((const void*)rnn_main,
                                     dim3(NBLOCKS), dim3(NTHREADS),
                                     args, 0, stream);

    rnn_out<<<dim3((BB * TT) / 4), dim3(256), 0, stream>>>(hidden, W_out, outputs);
    rnn_tcr<<<dim3(1), dim3(256), 0, stream>>>(partials, tcr);
}

// Round 18
// 987.564 us; speedup vs baseline: 10.7505x; 1.2052x over previous
//
#include <hip/hip_runtime.h>
#include <math.h>

// leaky_current_RNN: B=128, T=512, I=4, H=512, O=3, alpha=0.5, n_reg=256.
// R18 = exact revert to R10 (best measured: 987us, absmax 0.0039).
// Structure: 4-block groups (column-split W_rec, 128 f32 weights/thread in
// unified VGPR/AGPR file), two cohorts (rows g and 64+g) in alternating
// phases so each cohort's LLC publish->poll latency hides under the other's
// matvec; agent-scope self-validating (value|tag) u64 exchange; pk_fma
// matvec (row-scalar broadcast via op_sel_hi[0]=0); finalize on waves 0-1
// (full-wave coalesced publishes; waves 2-7 proceed to the next poll).
// Verdict from R11-R17 probes: drain-free barriers/ring-polls/prefetch null;
// AGPR clobber broken; 1-CU-per-row infeasible (512 regs/SIMD pool);
// acc-split + finalize-spread regress. This is the structure's plateau.

#define BB 128
#define TT 512
#define II 4
#define HH 512
#define OO 3
#define NREG_ 256

#define NTHREADS 512
#define MEMBERS 4
#define NGROUPS 64
#define NBLOCKS (NGROUPS * MEMBERS)

// d_ws layout (bytes): adat u64[2 coh][2 slot][64 g][512 col] = 1 MB
#define WS_PART  (2 * 2 * NGROUPS * HH * 8)

typedef unsigned long long u64;
typedef unsigned int u32;
typedef __attribute__((ext_vector_type(2))) float f32x2;

__device__ __forceinline__ u64 aload(const u64* p) {
    return __hip_atomic_load(p, __ATOMIC_RELAXED, __HIP_MEMORY_SCOPE_AGENT);
}
__device__ __forceinline__ void astore(u64* p, u64 v) {
    __hip_atomic_store(p, v, __ATOMIC_RELAXED, __HIP_MEMORY_SCOPE_AGENT);
}
__device__ __forceinline__ float fast_tanh(float x) {
    float ax = fabsf(x);
    float e  = __expf(2.0f * ax);
    float r  = 1.0f - 2.0f * __builtin_amdgcn_rcpf(e + 1.0f);
    return copysignf(r, x);
}

#define R16X(M) M(0) M(1) M(2) M(3) M(4) M(5) M(6) M(7) \
                M(8) M(9) M(10) M(11) M(12) M(13) M(14) M(15)

// Weight pairs: w.x = W[k][memb*128+lane], w.y = W[k][memb*128+64+lane]
#define WLD(Q) \
    f32x2 w##Q##a, w##Q##b, w##Q##c, w##Q##d; \
    w##Q##a.x = Wp[(size_t)(4*Q+0)*HH]; w##Q##a.y = Wp[(size_t)(4*Q+0)*HH+64]; \
    w##Q##b.x = Wp[(size_t)(4*Q+1)*HH]; w##Q##b.y = Wp[(size_t)(4*Q+1)*HH+64]; \
    w##Q##c.x = Wp[(size_t)(4*Q+2)*HH]; w##Q##c.y = Wp[(size_t)(4*Q+2)*HH+64]; \
    w##Q##d.x = Wp[(size_t)(4*Q+3)*HH]; w##Q##d.y = Wp[(size_t)(4*Q+3)*HH+64];

// acc = (colA, colB) for ONE row: row-scalar broadcast via op_sel_hi[0]=0.
#define KSTEP(K, W) { \
    u32 s_ = __builtin_amdgcn_readlane(__float_as_uint(ar), (K)); \
    u64 ss = (u64)s_; \
    asm("v_pk_fma_f32 %0, %1, %2, %0 op_sel_hi:[0,1,1]" \
        : "+v"(acc) : "s"(ss), "v"(W)); }

#define MV(Q) KSTEP(4*Q+0, w##Q##a) KSTEP(4*Q+1, w##Q##b) \
              KSTEP(4*Q+2, w##Q##c) KSTEP(4*Q+3, w##Q##d)

// adat index: ((coh*2 + slot)*NGROUPS + g)*HH + col ; word = (tanh(h) | tag)
__global__ __launch_bounds__(NTHREADS) __attribute__((amdgpu_waves_per_eu(2, 2)))
void rnn_main(const float* __restrict__ x,
              const float* __restrict__ h0,
              const float* __restrict__ W_rec,
              const float* __restrict__ W_in,
              const float* __restrict__ bias_rec,
              const float* __restrict__ bias_in,
              float* __restrict__ hidden,      // (T+1, B, H) region of d_out
              u64* __restrict__ adat,          // exchange buffer in d_ws
              float* __restrict__ partials)
{
    const int tid  = threadIdx.x;
    const int bid  = blockIdx.x;
    const int xcd  = bid & 7;
    const int onx  = bid >> 3;
    const int memb = onx & (MEMBERS - 1);
    const int g    = xcd * 8 + (onx >> 2);    // 0..63
    const int rA   = g;                       // cohort A row
    const int rB   = 64 + g;                  // cohort B row
    const int wid  = tid >> 6;                // k-window [64*wid, 64*wid+64)
    const int lane = tid & 63;

    __shared__ float sc_s[2][128][9];         // per-cohort split-k partials
    __shared__ float xbuf[2][TT * II];        // x rows (A, B)
    __shared__ float win_s[II][128];
    __shared__ float ub_s[128];
    __shared__ float red_s[NTHREADS / 64];

    // ---- one-time staging ----
    for (int idx = tid; idx < TT * II; idx += NTHREADS) {
        xbuf[0][idx] = x[(size_t)rA * (TT * II) + idx];
        xbuf[1][idx] = x[(size_t)rB * (TT * II) + idx];
    }
    if (tid < II * 128) {
        int i = tid >> 7, jj = tid & 127;
        win_s[i][jj] = W_in[i * HH + memb * 128 + jj];
    }
    if (tid < 128) {
        ub_s[tid] = bias_rec[memb * 128 + tid] + bias_in[memb * 128 + tid];
    }

    // ---- W_rec slice into registers as float2 (colA,colB) pairs ----
    const float* Wp = W_rec + (size_t)(wid * 64) * HH + memb * 128 + lane;
    R16X(WLD)

    // ---- prologue: publish tanh(h0) tag 1 for both cohorts ----
    const int fj  = tid & 127;                // finalize col (tid < 128)
    const int fjg = memb * 128 + fj;
    float hprevA = 0.0f, zprevA = 0.0f;
    float hprevB = 0.0f, zprevB = 0.0f;
    float racc = 0.0f;
    if (tid < 128) {
        hprevA = h0[(size_t)rA * HH + fjg];
        hprevB = h0[(size_t)rB * HH + fjg];
        u64 pA = (u64)__float_as_uint(fast_tanh(hprevA)) | ((u64)1u << 32);
        u64 pB = (u64)__float_as_uint(fast_tanh(hprevB)) | ((u64)1u << 32);
        astore(&adat[((size_t)(0 * 2 + 0) * NGROUPS + g) * HH + fjg], pA);
        astore(&adat[((size_t)(1 * 2 + 0) * NGROUPS + g) * HH + fjg], pB);
        hidden[(size_t)rA * HH + fjg] = hprevA;
        hidden[(size_t)rB * HH + fjg] = hprevB;
    }

#pragma unroll 1
    for (int t = 0; t < TT; ++t) {
        const int slot  = t & 1;
        const int slot2 = (t + 1) & 1;
        const u32 tagc  = (u32)(t + 1);
        const u64 tagp  = ((u64)(t + 2) << 32);

        // ================= PHASE A =================
        {
            const u64* pp = adat + ((size_t)(0 * 2 + slot) * NGROUPS + g) * HH
                            + wid * 64 + lane;
            u64 u;
            for (;;) {
                u = aload(pp);
                if (__all((u32)(u >> 32) == tagc)) break;
            }
            float ar = __uint_as_float((u32)u);

            f32x2 acc = {0.0f, 0.0f};
            R16X(MV)
            sc_s[0][lane][wid]      = acc.x;
            sc_s[0][lane + 64][wid] = acc.y;
        }
        __syncthreads();
        if (tid < 128) {
            float q0 = sc_s[0][fj][0], q1 = sc_s[0][fj][1];
            float q2 = sc_s[0][fj][2], q3 = sc_s[0][fj][3];
            float q4 = sc_s[0][fj][4], q5 = sc_s[0][fj][5];
            float q6 = sc_s[0][fj][6], q7 = sc_s[0][fj][7];
            float z = ((q0 + q1) + (q2 + q3)) + ((q4 + q5) + (q6 + q7));
            z += ub_s[fj];
            const float* xr = &xbuf[0][t * II];
            z = fmaf(xr[0], win_s[0][fj], z);
            z = fmaf(xr[1], win_s[1][fj], z);
            z = fmaf(xr[2], win_s[2][fj], z);
            z = fmaf(xr[3], win_s[3][fj], z);
            float hn = 0.5f * hprevA + 0.5f * z;
            u64 pv = (u64)__float_as_uint(fast_tanh(hn)) | tagp;
            astore(&adat[((size_t)(0 * 2 + slot2) * NGROUPS + g) * HH + fjg], pv);
            hidden[(size_t)(t + 1) * BB * HH + (size_t)rA * HH + fjg] = hn;
            if (fjg < NREG_) {
                float d1 = hn - hprevA;
                racc = fmaf(d1, d1, racc);
                if (t > 0) { float d2 = z - zprevA; racc = fmaf(d2, d2, racc); }
                zprevA = z;
            }
            hprevA = hn;
        }

        // ================= PHASE B =================
        {
            const u64* pp = adat + ((size_t)(1 * 2 + slot) * NGROUPS + g) * HH
                            + wid * 64 + lane;
            u64 u;
            for (;;) {
                u = aload(pp);
                if (__all((u32)(u >> 32) == tagc)) break;
            }
            float ar = __uint_as_float((u32)u);

            f32x2 acc = {0.0f, 0.0f};
            R16X(MV)
            sc_s[1][lane][wid]      = acc.x;
            sc_s[1][lane + 64][wid] = acc.y;
        }
        __syncthreads();
        if (tid < 128) {
            float q0 = sc_s[1][fj][0], q1 = sc_s[1][fj][1];
            float q2 = sc_s[1][fj][2], q3 = sc_s[1][fj][3];
            float q4 = sc_s[1][fj][4], q5 = sc_s[1][fj][5];
            float q6 = sc_s[1][fj][6], q7 = sc_s[1][fj][7];
            float z = ((q0 + q1) + (q2 + q3)) + ((q4 + q5) + (q6 + q7));
            z += ub_s[fj];
            const float* xr = &xbuf[1][t * II];
            z = fmaf(xr[0], win_s[0][fj], z);
            z = fmaf(xr[1], win_s[1][fj], z);
            z = fmaf(xr[2], win_s[2][fj], z);
            z = fmaf(xr[3], win_s[3][fj], z);
            float hn = 0.5f * hprevB + 0.5f * z;
            u64 pv = (u64)__float_as_uint(fast_tanh(hn)) | tagp;
            astore(&adat[((size_t)(1 * 2 + slot2) * NGROUPS + g) * HH + fjg], pv);
            hidden[(size_t)(t + 1) * BB * HH + (size_t)rB * HH + fjg] = hn;
            if (fjg < NREG_) {
                float d1 = hn - hprevB;
                racc = fmaf(d1, d1, racc);
                if (t > 0) { float d2 = z - zprevB; racc = fmaf(d2, d2, racc); }
                zprevB = z;
            }
            hprevB = hn;
        }
    }

    // ---- block-reduce reg partial (stored by ROLE for determinism) ----
    for (int off = 32; off; off >>= 1) racc += __shfl_down(racc, off);
    if ((tid & 63) == 0) red_s[tid >> 6] = racc;
    __syncthreads();
    if (tid == 0) {
        float s = 0.0f;
        for (int i = 0; i < NTHREADS / 64; ++i) s += red_s[i];
        partials[g * MEMBERS + memb] = s;
    }
}

// outputs[b][t][:] = hidden[t+1][b][:] @ W_out   (one wave per (b,t))
__global__ __launch_bounds__(256)
void rnn_out(const float* __restrict__ hidden,
             const float* __restrict__ W_out,
             float* __restrict__ outputs)
{
    __shared__ float wout_s[HH * OO];
    const int tid = threadIdx.x;
    for (int i = tid; i < HH * OO; i += 256) wout_s[i] = W_out[i];
    __syncthreads();

    const int gid  = blockIdx.x * 4 + (tid >> 6);
    const int lane = tid & 63;
    const int b = gid >> 9;
    const int t = gid & (TT - 1);
    const float* hp = hidden + (size_t)(t + 1) * BB * HH + (size_t)b * HH;

    float o0 = 0.0f, o1 = 0.0f, o2 = 0.0f;
#pragma unroll
    for (int q = 0; q < 8; ++q) {
        int k = lane + 64 * q;
        float hv = hp[k];
        o0 = fmaf(hv, wout_s[k * 3 + 0], o0);
        o1 = fmaf(hv, wout_s[k * 3 + 1], o1);
        o2 = fmaf(hv, wout_s[k * 3 + 2], o2);
    }
    for (int off = 32; off; off >>= 1) {
        o0 += __shfl_down(o0, off);
        o1 += __shfl_down(o1, off);
        o2 += __shfl_down(o2, off);
    }
    if (lane == 0) {
        float* op = outputs + (size_t)(b * TT + t) * OO;
        op[0] = o0; op[1] = o1; op[2] = o2;
    }
}

__global__ __launch_bounds__(256)
void rnn_tcr(const float* __restrict__ partials, float* __restrict__ tcr)
{
    __shared__ float red[4];
    const int tid = threadIdx.x;
    float v = partials[tid];
    for (int off = 32; off; off >>= 1) v += __shfl_down(v, off);
    if ((tid & 63) == 0) red[tid >> 6] = v;
    __syncthreads();
    if (tid == 0) {
        float s = red[0] + red[1] + red[2] + red[3];
        *tcr = s * (1.0f / ((float)TT * (float)BB * (float)NREG_));
    }
}

extern "C" void kernel_launch(void* const* d_in, const int* in_sizes, int n_in,
                              void* d_out, int out_size, void* d_ws, size_t ws_size,
                              hipStream_t stream)
{
    (void)in_sizes; (void)n_in; (void)out_size; (void)ws_size;

    const float* x     = (const float*)d_in[0];
    const float* h0    = (const float*)d_in[1];
    const float* W_rec = (const float*)d_in[2];
    const float* W_in  = (const float*)d_in[3];
    const float* W_out = (const float*)d_in[4];
    const float* brec  = (const float*)d_in[5];
    const float* bin   = (const float*)d_in[6];

    float* out     = (float*)d_out;
    float* outputs = out;
    float* hidden  = out + (size_t)BB * TT * OO;
    float* tcr     = out + (size_t)BB * TT * OO + (size_t)(TT + 1) * BB * HH;

    u64*   adat     = (u64*)d_ws;
    float* partials = (float*)((char*)d_ws + WS_PART);

    // zero exchange-buffer tags every call (graph replays reuse d_ws)
    (void)hipMemsetAsync(d_ws, 0, WS_PART, stream);

    void* args[] = { (void*)&x, (void*)&h0, (void*)&W_rec, (void*)&W_in,
                     (void*)&brec, (void*)&bin, (void*)&hidden,
                     (void*)&adat, (void*)&partials };
    (void)hipLaunchCooperativeKernel((const void*)rnn_main,
                                     dim3(NBLOCKS), dim3(NTHREADS),
                                     args, 0, stream);

    rnn_out<<<dim3((BB * TT) / 4), dim3(256), 0, stream>>>(hidden, W_out, outputs);
    rnn_tcr<<<dim3(1), dim3(256), 0, stream>>>(partials, tcr);
}